// Round 8
// baseline (192.066 us; speedup 1.0000x reference)
//
#include <hip/hip_runtime.h>

// ExpanderLinearLayer: out[M,N] = input[M,K] @ (W[N,K]*mask[N,K])^T
// M=16384, N=2048, K=2048, fp32 in/out.
// bf16 conversion + 256x256 MFMA GEMM (16x16x32). 64 phases:
// {STG; VMCNT(8); bar; [reads for t+1 pipelined in-cluster]; 32 MFMA; bar}
// with sched_group_barrier (MFMA,4)/(DS_READ,2) x8 pinning the read/MFMA
// interleave (R7 showed compiler serializes them otherwise), and column-band
// XCD mapping (tn = bid&7): each XCD's B-panel (1 MB) pins in its L2.

#define MDIM 16384
#define NDIM 2048
#define KDIM 2048

#define BM 256
#define BN 256
#define GRID_X ((MDIM / BM) * (NDIM / BN))  // 64*8 = 512

using f32x4   = __attribute__((ext_vector_type(4))) float;
using bf16x8  = __attribute__((ext_vector_type(8))) __bf16;
using ushort8 = __attribute__((ext_vector_type(8))) unsigned short;

__device__ __forceinline__ unsigned short f2bf(float f) {
  unsigned int u = __builtin_bit_cast(unsigned int, f);
  u = u + 0x7FFFu + ((u >> 16) & 1u);  // RNE
  return (unsigned short)(u >> 16);
}

// ---------------- conversion kernels ----------------

__global__ void convert_input_kernel(const float* __restrict__ in,
                                     unsigned short* __restrict__ out) {
  size_t base = ((size_t)blockIdx.x * blockDim.x + threadIdx.x) * 8;
  float4 a = *reinterpret_cast<const float4*>(in + base);
  float4 b = *reinterpret_cast<const float4*>(in + base + 4);
  ushort8 v;
  v[0] = f2bf(a.x); v[1] = f2bf(a.y); v[2] = f2bf(a.z); v[3] = f2bf(a.w);
  v[4] = f2bf(b.x); v[5] = f2bf(b.y); v[6] = f2bf(b.z); v[7] = f2bf(b.w);
  *reinterpret_cast<ushort8*>(out + base) = v;
}

__global__ void convert_weight_kernel(const float* __restrict__ w,
                                      const int* __restrict__ mk,
                                      unsigned short* __restrict__ out) {
  size_t base = ((size_t)blockIdx.x * blockDim.x + threadIdx.x) * 8;
  float4 a = *reinterpret_cast<const float4*>(w + base);
  float4 b = *reinterpret_cast<const float4*>(w + base + 4);
  int4 m0 = *reinterpret_cast<const int4*>(mk + base);
  int4 m1 = *reinterpret_cast<const int4*>(mk + base + 4);
  ushort8 v;
  v[0] = m0.x ? f2bf(a.x) : (unsigned short)0;
  v[1] = m0.y ? f2bf(a.y) : (unsigned short)0;
  v[2] = m0.z ? f2bf(a.z) : (unsigned short)0;
  v[3] = m0.w ? f2bf(a.w) : (unsigned short)0;
  v[4] = m1.x ? f2bf(b.x) : (unsigned short)0;
  v[5] = m1.y ? f2bf(b.y) : (unsigned short)0;
  v[6] = m1.z ? f2bf(b.z) : (unsigned short)0;
  v[7] = m1.w ? f2bf(b.w) : (unsigned short)0;
  *reinterpret_cast<ushort8*>(out + base) = v;
}

// ---------------- pipelined GEMM ----------------

__device__ __forceinline__ f32x4 MF(bf16x8 a, bf16x8 b, f32x4 c) {
  return __builtin_amdgcn_mfma_f32_16x16x32_bf16(a, b, c, 0, 0, 0);
}
__device__ __forceinline__ void bar() {
  asm volatile("" ::: "memory");
  __builtin_amdgcn_s_barrier();
  asm volatile("" ::: "memory");
}
#define VMCNT(n) asm volatile("s_waitcnt vmcnt(" #n ")" ::: "memory")

// LDS: per operand 4 slots [buf(2)][khalf(2)] of 256 rows x 32 k bf16 (16 KiB).
// Slot ring: phase t consumes slot t%4. Swizzle: 16-B chunk within 64-B row,
// chunk' = chunk ^ ((row>>1)&3) (conflict-free, verified R3). Applied on the
// pre-swizzled global SOURCE (gload_lds dest linear) and on ds_read addrs.
__global__ __launch_bounds__(512, 2) void gemm_pl(
    const unsigned short* __restrict__ Abf,
    const unsigned short* __restrict__ Bbf,
    float* __restrict__ C) {
  __shared__ __attribute__((aligned(16))) unsigned short Asl[4 * 8192];
  __shared__ __attribute__((aligned(16))) unsigned short Bsl[4 * 8192];

  // Column-band XCD mapping: dispatch round-robins bid%8 over XCDs, so
  // tn = bid&7 gives each XCD ONE column band (B-panel L2-pinned); all XCDs
  // sweep the same A-panel (tm = bid>>3) together (L3-hot).
  int bid = blockIdx.x;
  int tm = bid >> 3;
  int tn = bid & 7;
  int row0 = tm * BM, col0 = tn * BN;

  int t = threadIdx.x;
  int lane = t & 63, wid = t >> 6;
  int wr = wid >> 2, wc = wid & 3;       // 2 x 4 wave grid, wave tile 128x64
  int fr = lane & 15, fq = lane >> 4;

  // staging: thread handles chunks p0 and p0+64 (rows r0, r0+16; same swizzle
  // key since key=(r>>1)&3 is invariant under +16 rows).
  int p0 = (wid * 2 + 0) * 64 + lane;
  int r0 = p0 >> 2, kc0 = ((p0 & 3) ^ ((r0 >> 1) & 3)) * 8;  // inverse-swz src
  size_t offA0 = (size_t)(row0 + r0) * KDIM + kc0;
  size_t offB0 = (size_t)(col0 + r0) * KDIM + kc0;
  int ldsw0 = (wid * 2 + 0) * 512;  // elements; wave-uniform

  // frag ds_read offsets; row key (row>>1)&3 invariant under +16m/wave offsets
  int kxor = (fq ^ ((fr >> 1) & 3)) * 8;
  int aoff = (wr * 128 + fr) * 32 + kxor;
  int boff = (wc * 64 + fr) * 32 + kxor;

  f32x4 acc[8][4];
#pragma unroll
  for (int m = 0; m < 8; ++m)
#pragma unroll
    for (int n = 0; n < 4; ++n) acc[m][n] = f32x4{0.f, 0.f, 0.f, 0.f};

  bf16x8 afr[8], bfrA[4], bfrB[4];

#define SLOT_A(b, kh) (Asl + ((b) * 2 + (kh)) * 8192)
#define SLOT_B(b, kh) (Bsl + ((b) * 2 + (kh)) * 8192)

// stage one slot's A or B half-pair: rows r0 and r0+16 (offset +16*KDIM elems)
#define STG(slot, base, o0, ke) do {                                            \
  __builtin_amdgcn_global_load_lds(                                             \
      (const __attribute__((address_space(1))) void*)((base) + (o0) + (ke)),    \
      (__attribute__((address_space(3))) void*)((slot) + ldsw0), 16, 0, 0);     \
  __builtin_amdgcn_global_load_lds(                                             \
      (const __attribute__((address_space(1))) void*)((base) + (o0) + 32768 +   \
                                                      (ke)),                    \
      (__attribute__((address_space(3))) void*)((slot) + ldsw0 + 512), 16, 0,   \
      0);                                                                       \
} while (0)

// phase t: consume frags read at t-1 (afr + SETU), prefetch slot t+1 (rb,rkh)
// into afr (in-place after each m-group's last use) and SETR. Slot t+1 is
// retired by this phase's VMCNT and published by its barrier. The
// sched_group_barrier template (MFMA,4)/(DS_READ,2) x8 pins the read/MFMA
// interleave so the scheduler cannot sink the reads behind the cluster.
#define PHASE(rb, rkh, SETR, SETU, STAGES, WAITS) do {                          \
  STAGES;                                                                       \
  WAITS;                                                                        \
  bar();                                                                        \
  const unsigned short* _rpa = SLOT_A(rb, rkh) + aoff;                          \
  const unsigned short* _rpb = SLOT_B(rb, rkh) + boff;                          \
  __builtin_amdgcn_s_setprio(1);                                                \
  _Pragma("unroll")                                                             \
  for (int _n = 0; _n < 4; ++_n)                                                \
    SETR[_n] = *(const bf16x8*)(_rpb + _n * 512);                               \
  _Pragma("unroll")                                                             \
  for (int _m = 0; _m < 8; ++_m) {                                              \
    _Pragma("unroll")                                                           \
    for (int _n = 0; _n < 4; ++_n)                                              \
      acc[_m][_n] = MF(afr[_m], SETU[_n], acc[_m][_n]);                         \
    afr[_m] = *(const bf16x8*)(_rpa + _m * 512);                                \
  }                                                                             \
  _Pragma("unroll")                                                             \
  for (int _g = 0; _g < 8; ++_g) {                                              \
    __builtin_amdgcn_sched_group_barrier(0x008, 4, 0);  /* 4 MFMA   */          \
    __builtin_amdgcn_sched_group_barrier(0x100, 2, 0);  /* 2 DS_READ */         \
  }                                                                             \
  __builtin_amdgcn_s_setprio(0);                                                \
  bar();                                                                        \
} while (0)

  // prologue: stage slots s0,s1,s2 (12 vmem ops); retire s0 (VMCNT(8)),
  // publish, then read s0's frags (consumed by phase 0's cluster).
  STG(SLOT_A(0, 0), Abf, offA0, 0);
  STG(SLOT_B(0, 0), Bbf, offB0, 0);
  STG(SLOT_A(0, 1), Abf, offA0, 32);
  STG(SLOT_B(0, 1), Bbf, offB0, 32);
  STG(SLOT_A(1, 0), Abf, offA0, 64);
  STG(SLOT_B(1, 0), Bbf, offB0, 64);
  VMCNT(8);
  bar();
  {
    const unsigned short* pa = SLOT_A(0, 0) + aoff;
    const unsigned short* pb = SLOT_B(0, 0) + boff;
#pragma unroll
    for (int m = 0; m < 8; ++m) afr[m] = *(const bf16x8*)(pa + m * 512);
#pragma unroll
    for (int n = 0; n < 4; ++n) bfrA[n] = *(const bf16x8*)(pb + n * 512);
  }

  // main loop: phases t=0..59 (15 iters x 4). Phase t: STG slot t+3,
  // VMCNT(8) retires slot t+1, reads target slot t+1.
  for (int i = 0; i < 15; ++i) {
    int kb = i * 128;
    PHASE(0, 1, bfrB, bfrA, { STG(SLOT_A(1, 1), Abf, offA0, kb + 96);
                              STG(SLOT_B(1, 1), Bbf, offB0, kb + 96); }, VMCNT(8));
    PHASE(1, 0, bfrA, bfrB, { STG(SLOT_A(0, 0), Abf, offA0, kb + 128);
                              STG(SLOT_B(0, 0), Bbf, offB0, kb + 128); }, VMCNT(8));
    PHASE(1, 1, bfrB, bfrA, { STG(SLOT_A(0, 1), Abf, offA0, kb + 160);
                              STG(SLOT_B(0, 1), Bbf, offB0, kb + 160); }, VMCNT(8));
    PHASE(0, 0, bfrA, bfrB, { STG(SLOT_A(1, 0), Abf, offA0, kb + 192);
                              STG(SLOT_B(1, 0), Bbf, offB0, kb + 192); }, VMCNT(8));
  }
  // tail: phases 60..63. s63 staged at t=60; drain 8 -> 4 -> 0.
  PHASE(0, 1, bfrB, bfrA, { STG(SLOT_A(1, 1), Abf, offA0, 2016);
                            STG(SLOT_B(1, 1), Bbf, offB0, 2016); }, VMCNT(8));
  PHASE(1, 0, bfrA, bfrB, , VMCNT(4));
  PHASE(1, 1, bfrB, bfrA, , VMCNT(0));
  {  // phase 63: cluster only (frags already in regs; no barriers needed)
#pragma unroll
    for (int m = 0; m < 8; ++m)
#pragma unroll
      for (int n = 0; n < 4; ++n)
        acc[m][n] = MF(afr[m], bfrB[n], acc[m][n]);
  }

  // epilogue: C/D layout (verified m89) col=lane&15, row=(lane>>4)*4+reg
  size_t crow = (size_t)(row0 + wr * 128 + fq * 4);
  int ccol = col0 + wc * 64 + fr;
#pragma unroll
  for (int m = 0; m < 8; ++m)
#pragma unroll
    for (int n = 0; n < 4; ++n) {
      float* cp = C + (crow + m * 16) * NDIM + ccol + n * 16;
#pragma unroll
      for (int e = 0; e < 4; ++e) cp[(size_t)e * NDIM] = acc[m][n][e];
    }
#undef PHASE
#undef STG
#undef SLOT_A
#undef SLOT_B
}

// ---------------- fallback (fused conversion, 128^2 m97-structure) ----------

__global__ __launch_bounds__(256) void gemm_fused_fallback(
    const float* __restrict__ Afp,
    const float* __restrict__ Wfp,
    const int* __restrict__ Mk,
    float* __restrict__ C) {
  __shared__ unsigned short As[128 * 32];
  __shared__ unsigned short Bs[128 * 32];
  int bid = blockIdx.x;
  int nwg = (MDIM / 128) * (NDIM / 128);
  int wg = (bid & 7) * (nwg / 8) + (bid >> 3);
  int tm = wg >> 4, tn = wg & 15;
  int row0 = tm * 128, col0 = tn * 128;
  int t = threadIdx.x;
  int lane = t & 63, wv = t >> 6;
  int wr = wv >> 1, wc = wv & 1;
  int fr = lane & 15, fq = lane >> 4;
  f32x4 acc[4][4];
#pragma unroll
  for (int i = 0; i < 4; ++i)
#pragma unroll
    for (int j = 0; j < 4; ++j) acc[i][j] = f32x4{0.f, 0.f, 0.f, 0.f};
  for (int kt = 0; kt < KDIM; kt += 32) {
#pragma unroll
    for (int j = 0; j < 2; ++j) {
      int c = j * 256 + t;
      int r = c >> 2;
      int ko = (c & 3) * 8;
      const float* ga = Afp + (size_t)(row0 + r) * KDIM + kt + ko;
      float4 a0 = *reinterpret_cast<const float4*>(ga);
      float4 a1 = *reinterpret_cast<const float4*>(ga + 4);
      ushort8 va;
      va[0] = f2bf(a0.x); va[1] = f2bf(a0.y); va[2] = f2bf(a0.z); va[3] = f2bf(a0.w);
      va[4] = f2bf(a1.x); va[5] = f2bf(a1.y); va[6] = f2bf(a1.z); va[7] = f2bf(a1.w);
      *reinterpret_cast<ushort8*>(As + (size_t)c * 8) = va;
      const float* gw = Wfp + (size_t)(col0 + r) * KDIM + kt + ko;
      const int* gm = Mk + (size_t)(col0 + r) * KDIM + kt + ko;
      float4 w0 = *reinterpret_cast<const float4*>(gw);
      float4 w1 = *reinterpret_cast<const float4*>(gw + 4);
      int4 m0 = *reinterpret_cast<const int4*>(gm);
      int4 m1 = *reinterpret_cast<const int4*>(gm + 4);
      ushort8 vb;
      vb[0] = m0.x ? f2bf(w0.x) : (unsigned short)0;
      vb[1] = m0.y ? f2bf(w0.y) : (unsigned short)0;
      vb[2] = m0.z ? f2bf(w0.z) : (unsigned short)0;
      vb[3] = m0.w ? f2bf(w0.w) : (unsigned short)0;
      vb[4] = m1.x ? f2bf(w1.x) : (unsigned short)0;
      vb[5] = m1.y ? f2bf(w1.y) : (unsigned short)0;
      vb[6] = m1.z ? f2bf(w1.z) : (unsigned short)0;
      vb[7] = m1.w ? f2bf(w1.w) : (unsigned short)0;
      *reinterpret_cast<ushort8*>(Bs + (size_t)c * 8) = vb;
    }
    __syncthreads();
    bf16x8 af[4], bfr[4];
#pragma unroll
    for (int m2 = 0; m2 < 4; ++m2)
      af[m2] = *reinterpret_cast<const bf16x8*>(As + (wr * 64 + m2 * 16 + fr) * 32 + fq * 8);
#pragma unroll
    for (int n2 = 0; n2 < 4; ++n2)
      bfr[n2] = *reinterpret_cast<const bf16x8*>(Bs + (wc * 64 + n2 * 16 + fr) * 32 + fq * 8);
#pragma unroll
    for (int m2 = 0; m2 < 4; ++m2)
#pragma unroll
      for (int n2 = 0; n2 < 4; ++n2)
        acc[m2][n2] = MF(af[m2], bfr[n2], acc[m2][n2]);
    __syncthreads();
  }
#pragma unroll
  for (int m2 = 0; m2 < 4; ++m2)
#pragma unroll
    for (int n2 = 0; n2 < 4; ++n2) {
      size_t r0 = (size_t)(row0 + wr * 64 + m2 * 16 + fq * 4);
      size_t c0 = (size_t)(col0 + wc * 64 + n2 * 16 + fr);
#pragma unroll
      for (int i = 0; i < 4; ++i) C[(r0 + i) * NDIM + c0] = acc[m2][n2][i];
    }
}

// ---------------- launch ----------------

extern "C" void kernel_launch(void* const* d_in, const int* in_sizes, int n_in,
                              void* d_out, int out_size, void* d_ws, size_t ws_size,
                              hipStream_t stream) {
  const float* input  = (const float*)d_in[0];
  const float* weight = (const float*)d_in[1];
  const int*   mask   = (const int*)d_in[2];
  float* out = (float*)d_out;

  const size_t needA = (size_t)MDIM * KDIM * sizeof(unsigned short);
  const size_t needB = (size_t)NDIM * KDIM * sizeof(unsigned short);

  if (ws_size >= needA + needB) {
    unsigned short* Abf = (unsigned short*)d_ws;
    unsigned short* Bbf = (unsigned short*)((char*)d_ws + needA);
    convert_input_kernel<<<(MDIM * (size_t)KDIM / 8) / 256, 256, 0, stream>>>(input, Abf);
    convert_weight_kernel<<<(NDIM * (size_t)KDIM / 8) / 256, 256, 0, stream>>>(weight, mask, Bbf);
    gemm_pl<<<GRID_X, 512, 0, stream>>>(Abf, Bbf, out);
  } else {
    int nwg = (MDIM / 128) * (NDIM / 128);
    gemm_fused_fallback<<<nwg, 256, 0, stream>>>(input, weight, mask, out);
  }
}

// Round 9
// 187.324 us; speedup vs baseline: 1.0253x; 1.0253x over previous
//
#include <hip/hip_runtime.h>

// ExpanderLinearLayer: out[M,N] = input[M,K] @ (W[N,K]*mask[N,K])^T
// M=16384, N=2048, K=2048, fp32 in/out.
// bf16 conversion + 256x128-tile MFMA GEMM (16x16x32), 8 waves x (64x64),
// LDS ring A x3 + B x2 = 64 KiB -> 2 blocks/CU (16 waves/CU): sibling-block
// TLP fills barrier/vmcnt/LDS-drain idle (R2-R8 all showed read+MFMA
// serialization at 1 block/CU lockstep, MfmaUtil stuck ~40%).
// Per phase (BK=32): {stage A(t+2),B(t+1); VMCNT(3); bar; 8 ds_read;
// 16 MFMA (setprio); bar}. A lead 2 phases, B lead 1 phase (both > HBM lat).

#define MDIM 16384
#define NDIM 2048
#define KDIM 2048

#define BM 256
#define BN 128
#define GRID_X ((MDIM / BM) * (NDIM / BN))  // 64*16 = 1024

using f32x4   = __attribute__((ext_vector_type(4))) float;
using bf16x8  = __attribute__((ext_vector_type(8))) __bf16;
using ushort8 = __attribute__((ext_vector_type(8))) unsigned short;

__device__ __forceinline__ unsigned short f2bf(float f) {
  unsigned int u = __builtin_bit_cast(unsigned int, f);
  u = u + 0x7FFFu + ((u >> 16) & 1u);  // RNE
  return (unsigned short)(u >> 16);
}

// ---------------- conversion kernels ----------------

__global__ void convert_input_kernel(const float* __restrict__ in,
                                     unsigned short* __restrict__ out) {
  size_t base = ((size_t)blockIdx.x * blockDim.x + threadIdx.x) * 8;
  float4 a = *reinterpret_cast<const float4*>(in + base);
  float4 b = *reinterpret_cast<const float4*>(in + base + 4);
  ushort8 v;
  v[0] = f2bf(a.x); v[1] = f2bf(a.y); v[2] = f2bf(a.z); v[3] = f2bf(a.w);
  v[4] = f2bf(b.x); v[5] = f2bf(b.y); v[6] = f2bf(b.z); v[7] = f2bf(b.w);
  *reinterpret_cast<ushort8*>(out + base) = v;
}

__global__ void convert_weight_kernel(const float* __restrict__ w,
                                      const int* __restrict__ mk,
                                      unsigned short* __restrict__ out) {
  size_t base = ((size_t)blockIdx.x * blockDim.x + threadIdx.x) * 8;
  float4 a = *reinterpret_cast<const float4*>(w + base);
  float4 b = *reinterpret_cast<const float4*>(w + base + 4);
  int4 m0 = *reinterpret_cast<const int4*>(mk + base);
  int4 m1 = *reinterpret_cast<const int4*>(mk + base + 4);
  ushort8 v;
  v[0] = m0.x ? f2bf(a.x) : (unsigned short)0;
  v[1] = m0.y ? f2bf(a.y) : (unsigned short)0;
  v[2] = m0.z ? f2bf(a.z) : (unsigned short)0;
  v[3] = m0.w ? f2bf(a.w) : (unsigned short)0;
  v[4] = m1.x ? f2bf(b.x) : (unsigned short)0;
  v[5] = m1.y ? f2bf(b.y) : (unsigned short)0;
  v[6] = m1.z ? f2bf(b.z) : (unsigned short)0;
  v[7] = m1.w ? f2bf(b.w) : (unsigned short)0;
  *reinterpret_cast<ushort8*>(out + base) = v;
}

// ---------------- 2-blocks/CU GEMM ----------------

__device__ __forceinline__ f32x4 MF(bf16x8 a, bf16x8 b, f32x4 c) {
  return __builtin_amdgcn_mfma_f32_16x16x32_bf16(a, b, c, 0, 0, 0);
}
__device__ __forceinline__ void bar() {
  asm volatile("" ::: "memory");
  __builtin_amdgcn_s_barrier();
  asm volatile("" ::: "memory");
}
#define VMCNT(n) asm volatile("s_waitcnt vmcnt(" #n ")" ::: "memory")

// LDS: A ring 3 slots of [256 rows][32 k] bf16 (16 KiB), B ring 2 slots of
// [128 rows][32 k] (8 KiB) -> 64 KiB total, 2 blocks/CU. Slot for phase t:
// A = t%3, B = t%2; stage at t targets A (t+2)%3, B (t+1)%2.
// Swizzle (verified conflict-free R3): 16-B chunk' = chunk ^ ((row>>1)&3),
// applied on pre-swizzled global source (gload_lds dest linear) and ds_read.
__global__ __launch_bounds__(512, 4) void gemm_tlp(
    const unsigned short* __restrict__ Abf,
    const unsigned short* __restrict__ Bbf,
    float* __restrict__ C) {
  __shared__ __attribute__((aligned(16))) unsigned short Asl[3 * 8192];
  __shared__ __attribute__((aligned(16))) unsigned short Bsl[2 * 4096];

  // bijective XCD swizzle (1024 % 8 == 0): consecutive wgs on one XCD share
  // the same A panel (tm), rotating tn -> good L2/L3 locality (R3: 98 MB).
  int bid = blockIdx.x;
  int wgs = (bid & 7) * (GRID_X / 8) + (bid >> 3);
  int tm = wgs >> 4;  // NDIM/BN == 16
  int tn = wgs & 15;
  int row0 = tm * BM, col0 = tn * BN;

  int t = threadIdx.x;
  int lane = t & 63, wid = t >> 6;
  int wr = wid >> 1, wc = wid & 1;       // 4 x 2 wave grid, wave tile 64x64
  int fr = lane & 15, fq = lane >> 4;

  // staging A: thread covers chunks p0=(wid*2)*64+lane and p0+64
  int p0 = (wid * 2) * 64 + lane;
  int ra0 = p0 >> 2, ka0 = ((p0 & 3) ^ ((ra0 >> 1) & 3)) * 8;
  int p1 = p0 + 64;
  int ra1 = p1 >> 2, ka1 = ((p1 & 3) ^ ((ra1 >> 1) & 3)) * 8;
  size_t offA0 = (size_t)(row0 + ra0) * KDIM + ka0;
  size_t offA1 = (size_t)(row0 + ra1) * KDIM + ka1;
  int ldswA0 = (wid * 2) * 512, ldswA1 = (wid * 2 + 1) * 512;
  // staging B: thread covers chunk q = wid*64+lane
  int q = wid * 64 + lane;
  int rb = q >> 2, kb_ = ((q & 3) ^ ((rb >> 1) & 3)) * 8;
  size_t offB0 = (size_t)(col0 + rb) * KDIM + kb_;
  int ldswB = wid * 512;

  // frag ds_read offsets; key (row>>1)&3 invariant under +16/64 row offsets
  int kxor = (fq ^ ((fr >> 1) & 3)) * 8;
  int aoff = (wr * 64 + fr) * 32 + kxor;
  int boff = (wc * 64 + fr) * 32 + kxor;

  f32x4 acc[4][4];
#pragma unroll
  for (int m = 0; m < 4; ++m)
#pragma unroll
    for (int n = 0; n < 4; ++n) acc[m][n] = f32x4{0.f, 0.f, 0.f, 0.f};

#define STGA(sa, ke) do {                                                       \
  __builtin_amdgcn_global_load_lds(                                             \
      (const __attribute__((address_space(1))) void*)(Abf + offA0 + (ke)),      \
      (__attribute__((address_space(3))) void*)(Asl + (sa) * 8192 + ldswA0),    \
      16, 0, 0);                                                                \
  __builtin_amdgcn_global_load_lds(                                             \
      (const __attribute__((address_space(1))) void*)(Abf + offA1 + (ke)),      \
      (__attribute__((address_space(3))) void*)(Asl + (sa) * 8192 + ldswA1),    \
      16, 0, 0);                                                                \
} while (0)
#define STGB(sb, ke) do {                                                       \
  __builtin_amdgcn_global_load_lds(                                             \
      (const __attribute__((address_space(1))) void*)(Bbf + offB0 + (ke)),      \
      (__attribute__((address_space(3))) void*)(Bsl + (sb) * 4096 + ldswB),     \
      16, 0, 0);                                                                \
} while (0)

// phase: consume A slot sa, B slot sb. Stage first (issue early), counted
// vmcnt, barrier publishes all waves' staged slots, then reads + 16 MFMA.
// Sibling block on the CU fills our barrier/drain windows (2 blocks/CU).
#define PH(sa, sb, STAGES, WAITS) do {                                          \
  STAGES;                                                                       \
  WAITS;                                                                        \
  bar();                                                                        \
  const unsigned short* _ap = Asl + (sa) * 8192 + aoff;                         \
  const unsigned short* _bp = Bsl + (sb) * 4096 + boff;                         \
  bf16x8 _af[4], _bf[4];                                                        \
  _Pragma("unroll")                                                             \
  for (int _m = 0; _m < 4; ++_m) _af[_m] = *(const bf16x8*)(_ap + _m * 512);    \
  _Pragma("unroll")                                                             \
  for (int _n = 0; _n < 4; ++_n) _bf[_n] = *(const bf16x8*)(_bp + _n * 512);    \
  __builtin_amdgcn_s_setprio(1);                                                \
  _Pragma("unroll")                                                             \
  for (int _m = 0; _m < 4; ++_m)                                                \
    _Pragma("unroll")                                                           \
    for (int _n = 0; _n < 4; ++_n)                                              \
      acc[_m][_n] = MF(_af[_m], _bf[_n], acc[_m][_n]);                          \
  __builtin_amdgcn_s_setprio(0);                                                \
  bar();                                                                        \
} while (0)

  // prologue: A(0)->slot0, A(1)->slot1, B(0)->slot0 : 5 loads in flight.
  STGA(0, 0);
  STGA(1, 32);
  STGB(0, 0);

  // phases t=0..59: 10 x 6-phase unroll (slot pattern period lcm(3,2)=6).
  // Phase t: stage A(t+2)->(t+2)%3 @k=(t+2)*32, B(t+1)->(t+1)%2 @(t+1)*32;
  // VMCNT(3) retires everything staged before phase t-1's stages, i.e.
  // A(t) (staged t-2) and B(t) (staged t-1, last of that phase's 3).
  for (int i = 0; i < 10; ++i) {
    int kb = i * 192;
    PH(0, 0, { STGA(2, kb + 64);  STGB(1, kb + 32);  }, VMCNT(3));
    PH(1, 1, { STGA(0, kb + 96);  STGB(0, kb + 64);  }, VMCNT(3));
    PH(2, 0, { STGA(1, kb + 128); STGB(1, kb + 96);  }, VMCNT(3));
    PH(0, 1, { STGA(2, kb + 160); STGB(0, kb + 128); }, VMCNT(3));
    PH(1, 0, { STGA(0, kb + 192); STGB(1, kb + 160); }, VMCNT(3));
    PH(2, 1, { STGA(1, kb + 224); STGB(0, kb + 192); }, VMCNT(3));
  }
  // tail t=60..63 (k=1920..2016): stop staging past K; drain 3 -> 1 -> 0.
  PH(0, 0, { STGA(2, 1984); STGB(1, 1952); }, VMCNT(3));
  PH(1, 1, { STGA(0, 2016); STGB(0, 1984); }, VMCNT(3));
  PH(2, 0, { STGB(1, 2016); }, VMCNT(1));
  PH(0, 1, , VMCNT(0));

  // epilogue: C/D layout (verified m89) col=lane&15, row=(lane>>4)*4+reg
  size_t crow = (size_t)(row0 + wr * 64 + fq * 4);
  int ccol = col0 + wc * 64 + fr;
#pragma unroll
  for (int m = 0; m < 4; ++m)
#pragma unroll
    for (int n = 0; n < 4; ++n) {
      float* cp = C + (crow + m * 16) * NDIM + ccol + n * 16;
#pragma unroll
      for (int e = 0; e < 4; ++e) cp[(size_t)e * NDIM] = acc[m][n][e];
    }
#undef PH
#undef STGA
#undef STGB
}

// ---------------- fallback (fused conversion, 128^2 m97-structure) ----------

__global__ __launch_bounds__(256) void gemm_fused_fallback(
    const float* __restrict__ Afp,
    const float* __restrict__ Wfp,
    const int* __restrict__ Mk,
    float* __restrict__ C) {
  __shared__ unsigned short As[128 * 32];
  __shared__ unsigned short Bs[128 * 32];
  int bid = blockIdx.x;
  int nwg = (MDIM / 128) * (NDIM / 128);
  int wg = (bid & 7) * (nwg / 8) + (bid >> 3);
  int tm = wg >> 4, tn = wg & 15;
  int row0 = tm * 128, col0 = tn * 128;
  int t = threadIdx.x;
  int lane = t & 63, wv = t >> 6;
  int wr = wv >> 1, wc = wv & 1;
  int fr = lane & 15, fq = lane >> 4;
  f32x4 acc[4][4];
#pragma unroll
  for (int i = 0; i < 4; ++i)
#pragma unroll
    for (int j = 0; j < 4; ++j) acc[i][j] = f32x4{0.f, 0.f, 0.f, 0.f};
  for (int kt = 0; kt < KDIM; kt += 32) {
#pragma unroll
    for (int j = 0; j < 2; ++j) {
      int c = j * 256 + t;
      int r = c >> 2;
      int ko = (c & 3) * 8;
      const float* ga = Afp + (size_t)(row0 + r) * KDIM + kt + ko;
      float4 a0 = *reinterpret_cast<const float4*>(ga);
      float4 a1 = *reinterpret_cast<const float4*>(ga + 4);
      ushort8 va;
      va[0] = f2bf(a0.x); va[1] = f2bf(a0.y); va[2] = f2bf(a0.z); va[3] = f2bf(a0.w);
      va[4] = f2bf(a1.x); va[5] = f2bf(a1.y); va[6] = f2bf(a1.z); va[7] = f2bf(a1.w);
      *reinterpret_cast<ushort8*>(As + (size_t)c * 8) = va;
      const float* gw = Wfp + (size_t)(col0 + r) * KDIM + kt + ko;
      const int* gm = Mk + (size_t)(col0 + r) * KDIM + kt + ko;
      float4 w0 = *reinterpret_cast<const float4*>(gw);
      float4 w1 = *reinterpret_cast<const float4*>(gw + 4);
      int4 m0 = *reinterpret_cast<const int4*>(gm);
      int4 m1 = *reinterpret_cast<const int4*>(gm + 4);
      ushort8 vb;
      vb[0] = m0.x ? f2bf(w0.x) : (unsigned short)0;
      vb[1] = m0.y ? f2bf(w0.y) : (unsigned short)0;
      vb[2] = m0.z ? f2bf(w0.z) : (unsigned short)0;
      vb[3] = m0.w ? f2bf(w0.w) : (unsigned short)0;
      vb[4] = m1.x ? f2bf(w1.x) : (unsigned short)0;
      vb[5] = m1.y ? f2bf(w1.y) : (unsigned short)0;
      vb[6] = m1.z ? f2bf(w1.z) : (unsigned short)0;
      vb[7] = m1.w ? f2bf(w1.w) : (unsigned short)0;
      *reinterpret_cast<ushort8*>(Bs + (size_t)c * 8) = vb;
    }
    __syncthreads();
    bf16x8 af[4], bfr[4];
#pragma unroll
    for (int m2 = 0; m2 < 4; ++m2)
      af[m2] = *reinterpret_cast<const bf16x8*>(As + (wr * 64 + m2 * 16 + fr) * 32 + fq * 8);
#pragma unroll
    for (int n2 = 0; n2 < 4; ++n2)
      bfr[n2] = *reinterpret_cast<const bf16x8*>(Bs + (wc * 64 + n2 * 16 + fr) * 32 + fq * 8);
#pragma unroll
    for (int m2 = 0; m2 < 4; ++m2)
#pragma unroll
      for (int n2 = 0; n2 < 4; ++n2)
        acc[m2][n2] = MF(af[m2], bfr[n2], acc[m2][n2]);
    __syncthreads();
  }
#pragma unroll
  for (int m2 = 0; m2 < 4; ++m2)
#pragma unroll
    for (int n2 = 0; n2 < 4; ++n2) {
      size_t r0 = (size_t)(row0 + wr * 64 + m2 * 16 + fq * 4);
      size_t c0 = (size_t)(col0 + wc * 64 + n2 * 16 + fr);
#pragma unroll
      for (int i = 0; i < 4; ++i) C[(r0 + i) * NDIM + c0] = acc[m2][n2][i];
    }
}

// ---------------- launch ----------------

extern "C" void kernel_launch(void* const* d_in, const int* in_sizes, int n_in,
                              void* d_out, int out_size, void* d_ws, size_t ws_size,
                              hipStream_t stream) {
  const float* input  = (const float*)d_in[0];
  const float* weight = (const float*)d_in[1];
  const int*   mask   = (const int*)d_in[2];
  float* out = (float*)d_out;

  const size_t needA = (size_t)MDIM * KDIM * sizeof(unsigned short);
  const size_t needB = (size_t)NDIM * KDIM * sizeof(unsigned short);

  if (ws_size >= needA + needB) {
    unsigned short* Abf = (unsigned short*)d_ws;
    unsigned short* Bbf = (unsigned short*)((char*)d_ws + needA);
    convert_input_kernel<<<(MDIM * (size_t)KDIM / 8) / 256, 256, 0, stream>>>(input, Abf);
    convert_weight_kernel<<<(NDIM * (size_t)KDIM / 8) / 256, 256, 0, stream>>>(weight, mask, Bbf);
    gemm_tlp<<<GRID_X, 512, 0, stream>>>(Abf, Bbf, out);
  } else {
    int nwg = (MDIM / 128) * (NDIM / 128);
    gemm_fused_fallback<<<nwg, 256, 0, stream>>>(input, weight, mask, out);
  }
}